// Round 2
// baseline (230.674 us; speedup 1.0000x reference)
//
#include <hip/hip_runtime.h>

// Problem constants
#define V 32
#define CH 128
#define SP 4096   // 64*64

typedef __attribute__((ext_vector_type(8))) short bf16x8;
typedef __attribute__((ext_vector_type(4))) float f32x4;

__device__ __forceinline__ unsigned short bf16rne(float x) {
    union { float f; unsigned u; } v; v.f = x;
    unsigned r = v.u + 0x7fff + ((v.u >> 16) & 1);
    return (unsigned short)(r >> 16);
}

// XOR swizzle on the 8-elem k-block index; keeps both staging b32 writes and
// fragment b128 reads <=2-way bank conflicts (free on gfx950, m136).
__device__ __forceinline__ int xswz(int s) { return (s & 7) ^ ((s >> 2) & 7); }

// row pointer into xsm for the "j" (mixing) index at channel-residue r
__device__ __forceinline__ const float* xsm_row(const float* xsm, int j, int r) {
    return xsm + ((size_t)((j >> 2) * CH + (j & 3) * 32 + r)) * SP;
}

// ---------------------------------------------------------------------------
// prep_w: conv_w f32 [128][512] -> 4 bf16 slabs [sigma][o][c'] stride 136
// ---------------------------------------------------------------------------
__global__ __launch_bounds__(256) void prep_w(const float* __restrict__ W,
                                              unsigned short* __restrict__ Wpad)
{
    int row = blockIdx.x;           // 0..511 = sigma*128 + o
    int j = threadIdx.x;
    if (j < 136) {
        int sigma = row >> 7, o = row & 127;
        float v = (j < 128) ? W[o * 512 + sigma * 128 + j] : 0.f;
        Wpad[row * 136 + j] = bf16rne(v);
    }
}

// ---------------------------------------------------------------------------
// conv_lo: MFMA 1x1 conv partial at low res.  out[v,o,s] = sum_c W*x  (nph
// phases).  Tile M=128 o x N=64 s x K=128/phase.  grid (spatial/64, 32 v).
// W fragments read straight from global (34.8KB slab, L2-resident) -- no LDS
// staging.  Operands swapped vs v1: D row = s (reg idx) -> float4 stores.
// ---------------------------------------------------------------------------
__global__ __launch_bounds__(256, 4) void conv_lo(
    const float* __restrict__ xa, const float* __restrict__ xb,
    const unsigned short* __restrict__ WA, const unsigned short* __restrict__ WB,
    int spatial, int nph, float* __restrict__ outbuf)
{
    __shared__ __align__(16) unsigned short Xl[64 * 128];
    const int v = blockIdx.y, sc = blockIdx.x, tid = threadIdx.x;
    const int lane = tid & 63, w = tid >> 6;
    const int l15 = lane & 15, quad = lane >> 4;
    const int o0 = (w >> 1) * 64, s0 = (w & 1) * 32;
    const int sq = tid & 15, cp0 = tid >> 4;

    f32x4 acc[4][2];
#pragma unroll
    for (int it = 0; it < 4; ++it)
#pragma unroll
        for (int st = 0; st < 2; ++st) acc[it][st] = (f32x4){0.f, 0.f, 0.f, 0.f};

#pragma unroll 1
    for (int ph = 0; ph < nph; ++ph) {
        if (ph) __syncthreads();
        const float* xp = ph ? xb : xa;
        const unsigned short* wp = ph ? WB : WA;
        // stage X tile transposed: [128 c][64 s] f32 -> Xl[s][c] bf16 (swizzled)
        const float* xbase = xp + (size_t)v * CH * spatial + sc * 64;
#pragma unroll
        for (int rep = 0; rep < 4; ++rep) {
            int c = (cp0 + rep * 16) * 2;
            const float* r0 = xbase + (size_t)c * spatial + sq * 4;
            float4 va = *(const float4*)r0;
            float4 vb = *(const float4*)(r0 + spatial);
            float a4[4] = {va.x, va.y, va.z, va.w};
            float b4[4] = {vb.x, vb.y, vb.z, vb.w};
#pragma unroll
            for (int i = 0; i < 4; ++i) {
                int s = sq * 4 + i;
                ushort2 pk; pk.x = bf16rne(a4[i]); pk.y = bf16rne(b4[i]);
                *(ushort2*)&Xl[s * 128 + (((c >> 3) ^ xswz(s)) * 8) + (c & 7)] = pk;
            }
        }
        __syncthreads();
#pragma unroll
        for (int ks = 0; ks < 4; ++ks) {
            int kb = ks * 4 + quad;
            bf16x8 af[4], bfr[2];
#pragma unroll
            for (int it = 0; it < 4; ++it)
                af[it] = *(const bf16x8*)&wp[(o0 + it * 16 + l15) * 136 + ks * 32 + quad * 8];
#pragma unroll
            for (int st = 0; st < 2; ++st) {
                int s = s0 + st * 16 + l15;
                bfr[st] = *(const bf16x8*)&Xl[s * 128 + ((kb ^ xswz(s)) * 8)];
            }
#pragma unroll
            for (int it = 0; it < 4; ++it)
#pragma unroll
                for (int st = 0; st < 2; ++st)
                    acc[it][st] = __builtin_amdgcn_mfma_f32_16x16x32_bf16(
                        bfr[st], af[it], acc[it][st], 0, 0, 0);
        }
    }
    // epilogue: D row = s (quad*4+reg), col = o (l15) -> float4 stores
#pragma unroll
    for (int it = 0; it < 4; ++it) {
        int o = o0 + it * 16 + l15;
        float* orow = outbuf + ((size_t)(v * CH + o)) * spatial + sc * 64;
#pragma unroll
        for (int st = 0; st < 2; ++st) {
            int sb = s0 + st * 16 + quad * 4;
            *(f32x4*)(orow + sb) = acc[it][st];
        }
    }
}

// ---------------------------------------------------------------------------
// conv_full: x1 MFMA conv (K=128) + upsampled conv2/conv34 + bias -> xsm,
// plus gap[v][o] partial sums.  grid (64 sc, 32 v).
// ---------------------------------------------------------------------------
__global__ __launch_bounds__(256, 4) void conv_full(
    const float* __restrict__ x1, const unsigned short* __restrict__ W0,
    const float* __restrict__ bias, const float* __restrict__ conv2,
    const float* __restrict__ conv34, float* __restrict__ xsm,
    float* __restrict__ gap)
{
    __shared__ __align__(16) unsigned short Xl[64 * 128];
    __shared__ float gscr[4][64];
    const int v = blockIdx.y, sc = blockIdx.x, tid = threadIdx.x;
    const int lane = tid & 63, w = tid >> 6;
    const int l15 = lane & 15, quad = lane >> 4;
    const int o0 = (w >> 1) * 64, s0 = (w & 1) * 32;
    const int sq = tid & 15, cp0 = tid >> 4;

    f32x4 acc[4][2];
#pragma unroll
    for (int it = 0; it < 4; ++it)
#pragma unroll
        for (int st = 0; st < 2; ++st) acc[it][st] = (f32x4){0.f, 0.f, 0.f, 0.f};

    // stage X tile transposed: [128 c][64 s] f32 -> Xl[s][c] bf16 (swizzled)
    const float* xbase = x1 + (size_t)v * CH * SP + sc * 64;
#pragma unroll
    for (int rep = 0; rep < 4; ++rep) {
        int c = (cp0 + rep * 16) * 2;
        const float* r0 = xbase + (size_t)c * SP + sq * 4;
        float4 va = *(const float4*)r0;
        float4 vb = *(const float4*)(r0 + SP);
        float a4[4] = {va.x, va.y, va.z, va.w};
        float b4[4] = {vb.x, vb.y, vb.z, vb.w};
#pragma unroll
        for (int i = 0; i < 4; ++i) {
            int s = sq * 4 + i;
            ushort2 pk; pk.x = bf16rne(a4[i]); pk.y = bf16rne(b4[i]);
            *(ushort2*)&Xl[s * 128 + (((c >> 3) ^ xswz(s)) * 8) + (c & 7)] = pk;
        }
    }
    __syncthreads();
#pragma unroll
    for (int ks = 0; ks < 4; ++ks) {
        int kb = ks * 4 + quad;
        bf16x8 af[4], bfr[2];
#pragma unroll
        for (int it = 0; it < 4; ++it)
            af[it] = *(const bf16x8*)&W0[(o0 + it * 16 + l15) * 136 + ks * 32 + quad * 8];
#pragma unroll
        for (int st = 0; st < 2; ++st) {
            int s = s0 + st * 16 + l15;
            bfr[st] = *(const bf16x8*)&Xl[s * 128 + ((kb ^ xswz(s)) * 8)];
        }
#pragma unroll
        for (int it = 0; it < 4; ++it)
#pragma unroll
            for (int st = 0; st < 2; ++st)
                acc[it][st] = __builtin_amdgcn_mfma_f32_16x16x32_bf16(
                    bfr[st], af[it], acc[it][st], 0, 0, 0);
    }

    // epilogue: + bias + up2(conv2) + up4(conv34); float4 stores; gap sums
    const float* c2row = conv2 + (size_t)v * CH * 1024 + (sc >> 1) * 32;
    const float* c34row = conv34 + (size_t)v * CH * 256 + (sc >> 2) * 16;
    float gs[4];
#pragma unroll
    for (int it = 0; it < 4; ++it) {
        int o = o0 + it * 16 + l15;
        float b = bias[o];
        float* orow = xsm + ((size_t)(v * CH + o)) * SP + sc * 64;
        const float* c2p = c2row + (size_t)o * 1024;
        const float* c34p = c34row + (size_t)o * 256;
        float lsum = 0.f;
#pragma unroll
        for (int st = 0; st < 2; ++st) {
            int sb = s0 + st * 16 + quad * 4;
            float2 c2v = *(const float2*)(c2p + (sb >> 1));
            float c34v = c34p[sb >> 2];
            f32x4 a = acc[it][st];
            f32x4 ov;
            ov[0] = a[0] + b + c2v.x + c34v;
            ov[1] = a[1] + b + c2v.x + c34v;
            ov[2] = a[2] + b + c2v.y + c34v;
            ov[3] = a[3] + b + c2v.y + c34v;
            *(f32x4*)(orow + sb) = ov;
            lsum += ov[0] + ov[1] + ov[2] + ov[3];
        }
        gs[it] = lsum;
    }
    // s-dimension now lives across quads -> reduce with xor 16, 32
#pragma unroll
    for (int m = 16; m < 64; m <<= 1)
#pragma unroll
        for (int k = 0; k < 4; ++k) gs[k] += __shfl_xor(gs[k], m, 64);
    if (quad == 0) {
#pragma unroll
        for (int it = 0; it < 4; ++it)
            gscr[w][it * 16 + l15] = gs[it];
    }
    __syncthreads();
    if (tid < 128) {
        int o = tid, b2 = (o >> 6) * 2;
        atomicAdd(&gap[v * CH + o], gscr[b2][o & 63] + gscr[b2 + 1][o & 63]);
    }
}

// ---------------------------------------------------------------------------
// build_G: gap sums -> c_q -> att_C -> softmax*weight -> Gs = G - I (bf16,
// padded stride 136, [i][j]).  grid 128 (i) x 128 (j).
// ---------------------------------------------------------------------------
__global__ __launch_bounds__(128) void build_G(
    const float* __restrict__ gap, const float* __restrict__ gammap,
    const float* __restrict__ weight, unsigned short* __restrict__ GsPad)
{
    __shared__ float cq[32][128];
    __shared__ float red[128];
    const int i = blockIdx.x, j = threadIdx.x;
    const float g = gammap[0];

    float gb = 0.f;
    for (int v = 0; v < 32; ++v) gb += gap[v * CH + j];
    gb = gb * (1.f / 32.f) * (1.f / 4096.f) * g;
    for (int v = 0; v < 32; ++v) cq[v][j] = gap[v * CH + j] * (1.f / 4096.f) + gb;
    __syncthreads();

    float a = 0.f;
    for (int v = 0; v < 32; ++v) a += cq[v][i] * cq[v][j];

    red[j] = a; __syncthreads();
    float m = -1e30f;
    for (int t = 0; t < 128; ++t) m = fmaxf(m, red[t]);
    __syncthreads();
    float e = __expf(a - m);
    red[j] = e; __syncthreads();
    float ssum = 0.f;
    for (int t = 0; t < 128; ++t) ssum += red[t];
    float cm = e / ssum * weight[j] + ((i == j) ? 1.f : 0.f);   // (C_mat + I)[i][j]
    __syncthreads();
    red[j] = cm; __syncthreads();
    float rs = 0.f;
    for (int t = (j & 3); t < 128; t += 4) rs += red[t];
    float gfull = cm + g * (1.f / 32.f) * rs;
    GsPad[i * 136 + j] = bf16rne(gfull - ((i == j) ? 1.f : 0.f));  // minus identity
}

// ---------------------------------------------------------------------------
// apply_G: out[i=(v,gg)][s] = sum_j Gs[i][j]*Xt[j][s] + xsm[i-row][s] (f32
// residual).  In-place on xsm: per-(r,sc) block read-set == write-set, and
// each lane's residual read address == its own store address.
// G fragments read straight from global (34.8KB, L2-resident).
// grid (64 sc, 32 r).
// ---------------------------------------------------------------------------
__global__ __launch_bounds__(256, 4) void apply_G(
    float* __restrict__ xsm, const unsigned short* __restrict__ GsPad)
{
    __shared__ __align__(16) unsigned short Xl[64 * 128];
    const int r = blockIdx.y, sc = blockIdx.x, tid = threadIdx.x;
    const int lane = tid & 63, w = tid >> 6;
    const int l15 = lane & 15, quad = lane >> 4;
    const int i0 = (w >> 1) * 64, s0 = (w & 1) * 32;
    const int sq = tid & 15, cp0 = tid >> 4;

    f32x4 acc[4][2];
#pragma unroll
    for (int it = 0; it < 4; ++it)
#pragma unroll
        for (int st = 0; st < 2; ++st) acc[it][st] = (f32x4){0.f, 0.f, 0.f, 0.f};

    // stage Xt[j][s] -> Xl[s][j] bf16 (swizzled); j rows gathered from xsm
#pragma unroll
    for (int rep = 0; rep < 4; ++rep) {
        int c = (cp0 + rep * 16) * 2;     // j pair
        const float* r0 = xsm_row(xsm, c, r) + sc * 64 + sq * 4;
        const float* r1 = xsm_row(xsm, c + 1, r) + sc * 64 + sq * 4;
        float4 va = *(const float4*)r0;
        float4 vb = *(const float4*)r1;
        float a4[4] = {va.x, va.y, va.z, va.w};
        float b4[4] = {vb.x, vb.y, vb.z, vb.w};
#pragma unroll
        for (int i = 0; i < 4; ++i) {
            int s = sq * 4 + i;
            ushort2 pk; pk.x = bf16rne(a4[i]); pk.y = bf16rne(b4[i]);
            *(ushort2*)&Xl[s * 128 + (((c >> 3) ^ xswz(s)) * 8) + (c & 7)] = pk;
        }
    }
    __syncthreads();
#pragma unroll
    for (int ks = 0; ks < 4; ++ks) {
        int kb = ks * 4 + quad;
        bf16x8 af[4], bfr[2];
#pragma unroll
        for (int it = 0; it < 4; ++it)
            af[it] = *(const bf16x8*)&GsPad[(i0 + it * 16 + l15) * 136 + ks * 32 + quad * 8];
#pragma unroll
        for (int st = 0; st < 2; ++st) {
            int s = s0 + st * 16 + l15;
            bfr[st] = *(const bf16x8*)&Xl[s * 128 + ((kb ^ xswz(s)) * 8)];
        }
#pragma unroll
        for (int it = 0; it < 4; ++it)
#pragma unroll
            for (int st = 0; st < 2; ++st)
                acc[it][st] = __builtin_amdgcn_mfma_f32_16x16x32_bf16(
                    bfr[st], af[it], acc[it][st], 0, 0, 0);
    }
    // epilogue: f32 residual (own write address) + store, float4 both ways
#pragma unroll
    for (int it = 0; it < 4; ++it) {
        int i = i0 + it * 16 + l15;
        float* rowp = (float*)xsm_row(xsm, i, r) + sc * 64;
#pragma unroll
        for (int st = 0; st < 2; ++st) {
            int sb = s0 + st * 16 + quad * 4;
            f32x4 res = *(const f32x4*)(rowp + sb);
            res += acc[it][st];
            *(f32x4*)(rowp + sb) = res;
        }
    }
}

// ---------------------------------------------------------------------------
extern "C" void kernel_launch(void* const* d_in, const int* in_sizes, int n_in,
                              void* d_out, int out_size, void* d_ws, size_t ws_size,
                              hipStream_t stream)
{
    const float* x1     = (const float*)d_in[0];
    const float* x2     = (const float*)d_in[1];
    const float* x3     = (const float*)d_in[2];
    const float* x4     = (const float*)d_in[3];
    const float* conv_w = (const float*)d_in[4];
    const float* conv_b = (const float*)d_in[5];
    const float* gamma  = (const float*)d_in[6];
    const float* weight = (const float*)d_in[7];
    // d_in[8] = lin_w: mathematically unused (row-constant softmax -> uniform)

    float* out = (float*)d_out;     // doubles as x_sm (in-place pass 2)
    float* ws  = (float*)d_ws;

    // ws layout (floats): conv2[4194304], conv34[1048576], gap[4096],
    //                     Wpad bf16 4*128*136 (34816 f), GsPad bf16 128*136 (8704 f)
    float* conv2  = ws;
    float* conv34 = ws + (size_t)4194304;
    float* gap    = ws + (size_t)5242880;
    unsigned short* Wpad  = (unsigned short*)(ws + (size_t)5246976);
    unsigned short* GsPad = (unsigned short*)(ws + (size_t)5281792);

    hipMemsetAsync(gap, 0, 4096 * sizeof(float), stream);

    prep_w<<<512, 256, 0, stream>>>(conv_w, Wpad);
    conv_lo<<<dim3(16, 32), 256, 0, stream>>>(x2, x2, Wpad + 1 * 128 * 136,
                                              Wpad + 1 * 128 * 136, 1024, 1, conv2);
    conv_lo<<<dim3(4, 32), 256, 0, stream>>>(x3, x4, Wpad + 2 * 128 * 136,
                                             Wpad + 3 * 128 * 136, 256, 2, conv34);
    conv_full<<<dim3(64, 32), 256, 0, stream>>>(x1, Wpad, conv_b, conv2, conv34, out, gap);
    build_G<<<128, 128, 0, stream>>>(gap, gamma, weight, GsPad);
    apply_G<<<dim3(64, 32), 256, 0, stream>>>(out, GsPad);
}